// Round 1
// baseline (27.859 us; speedup 1.0000x reference)
//
#include <hip/hip_runtime.h>

#define SEQ 256
#define NENV 64
#define NGROUPS 12
#define GDIM 128
#define ROWS (SEQ * NENV)           // 16384
#define WAVES_PER_BLOCK 4

// Kernel 1: fold Wg (128x128) with wa = Wa[128:256] -> v[128]
// v[d] = sum_a Wg[d][a] * Wa[128 + a]
__global__ void fold_wg_wa(const float* __restrict__ Wg,
                           const float* __restrict__ Wa,
                           float* __restrict__ v) {
    int d = threadIdx.x;            // 128 threads
    float acc = 0.0f;
#pragma unroll 8
    for (int a = 0; a < 128; ++a) {
        acc += Wg[d * 128 + a] * Wa[128 + a];
    }
    v[d] = acc;
}

// Kernel 2: one 64-lane wave per (s,e) row.
//   scores[g] = ge[row,g,:] . v          (robot/bias terms cancel in softmax)
//   weights   = softmax_g(scores)
//   weighted  = sum_g weights[g] * ge[row,g,:]
__global__ __launch_bounds__(WAVES_PER_BLOCK * 64)
void group_attn(const float* __restrict__ ge,     // (ROWS, 12, 128)
                const float* __restrict__ v,      // (128)
                float* __restrict__ out_weighted, // (ROWS, 128)
                float* __restrict__ out_weights)  // (ROWS, 12)
{
    const int wave = threadIdx.x >> 6;
    const int lane = threadIdx.x & 63;
    const int row  = blockIdx.x * WAVES_PER_BLOCK + wave;   // grid sized exactly

    const int half = lane >> 5;     // 0: even groups, 1: odd groups
    const int l32  = lane & 31;     // dim block: dims [l32*4, l32*4+3]

    const float* base = ge + (size_t)row * (NGROUPS * GDIM);

    // v fragment for my 4 dims (broadcast across halves/waves; L1-resident)
    const float4 vf = *reinterpret_cast<const float4*>(v + l32 * 4);

    // Load the whole 12x128 row: 6 steps x 64 lanes x float4 = 1536 floats.
    // Step t covers groups {2t (lanes 0..31), 2t+1 (lanes 32..63)}.
    float4 g[6];
    float  pdot[6];
#pragma unroll
    for (int t = 0; t < 6; ++t) {
        g[t] = *reinterpret_cast<const float4*>(base + t * 256 + lane * 4);
        pdot[t] = g[t].x * vf.x + g[t].y * vf.y + g[t].z * vf.z + g[t].w * vf.w;
    }

    // Reduce dots: 5-step butterfly within each 32-lane half, then one
    // cross-half exchange so every lane holds both groups' scores.
    float sc[12];
#pragma unroll
    for (int t = 0; t < 6; ++t) {
        float p = pdot[t];
        p += __shfl_xor(p, 1);
        p += __shfl_xor(p, 2);
        p += __shfl_xor(p, 4);
        p += __shfl_xor(p, 8);
        p += __shfl_xor(p, 16);
        float q = __shfl_xor(p, 32);
        sc[2 * t]     = half ? q : p;
        sc[2 * t + 1] = half ? p : q;
    }

    // Softmax over 12 scores (redundant in every lane; ~40 VALU ops)
    float m = sc[0];
#pragma unroll
    for (int i = 1; i < NGROUPS; ++i) m = fmaxf(m, sc[i]);
    float w[12];
    float sum = 0.0f;
#pragma unroll
    for (int i = 0; i < NGROUPS; ++i) {
        w[i] = __expf(sc[i] - m);
        sum += w[i];
    }
    const float inv = 1.0f / sum;
#pragma unroll
    for (int i = 0; i < NGROUPS; ++i) w[i] *= inv;

    // Weighted sum of group embeddings (data already in registers).
    float4 acc = make_float4(0.f, 0.f, 0.f, 0.f);
#pragma unroll
    for (int t = 0; t < 6; ++t) {
        const float wt = w[2 * t + half];
        acc.x += wt * g[t].x;
        acc.y += wt * g[t].y;
        acc.z += wt * g[t].z;
        acc.w += wt * g[t].w;
    }
    // Combine even-group half with odd-group half (same dims in lane^32).
    acc.x += __shfl_xor(acc.x, 32);
    acc.y += __shfl_xor(acc.y, 32);
    acc.z += __shfl_xor(acc.z, 32);
    acc.w += __shfl_xor(acc.w, 32);

    if (lane < 32) {
        *reinterpret_cast<float4*>(out_weighted + (size_t)row * GDIM + l32 * 4) = acc;
    } else if (lane < 32 + NGROUPS) {
        out_weights[(size_t)row * NGROUPS + (lane - 32)] = w[lane - 32];
    }
}

extern "C" void kernel_launch(void* const* d_in, const int* in_sizes, int n_in,
                              void* d_out, int out_size, void* d_ws, size_t ws_size,
                              hipStream_t stream) {
    // Inputs (setup_inputs order):
    // 0 robot_states (unused — cancels in softmax)
    // 1 group_embeddings (S,E,G,128)
    // 2 Wr (unused)  3 br (unused)
    // 4 Wg (128,128) 5 bg (unused)
    // 6 Wa (256,1)   7 ba (unused)
    const float* ge = (const float*)d_in[1];
    const float* Wg = (const float*)d_in[4];
    const float* Wa = (const float*)d_in[6];

    float* v = (float*)d_ws;                         // 128 floats
    float* out_weighted = (float*)d_out;             // ROWS*128
    float* out_weights  = out_weighted + (size_t)ROWS * GDIM;  // ROWS*12

    fold_wg_wa<<<1, 128, 0, stream>>>(Wg, Wa, v);
    group_attn<<<ROWS / WAVES_PER_BLOCK, WAVES_PER_BLOCK * 64, 0, stream>>>(
        ge, v, out_weighted, out_weights);
}